// Round 1
// baseline (749.697 us; speedup 1.0000x reference)
//
#include <hip/hip_runtime.h>
#include <math.h>

typedef _Float16 f16;
typedef _Float16 f16x2 __attribute__((ext_vector_type(2)));
typedef _Float16 f16x4 __attribute__((ext_vector_type(4)));
typedef _Float16 f16x8 __attribute__((ext_vector_type(8)));
typedef float    f32x4 __attribute__((ext_vector_type(4)));

#define PKRTZ(a, b) __builtin_bit_cast(f16x2, __builtin_amdgcn_cvt_pkrtz((a), (b)))

#define NN 8192
#define DD 64
#define KT 32
#define NQB 64
#define NWAVES 8
#define KPW (NN / NWAVES)      // 1024 keys per wave
#define NTILES (KPW / KT)      // 32

#define LOG2E 1.44269504088896f

// ---------------- kernel A: f32 -> f16 natural (Xn) + 32-key-tiled transpose (Xv) ----
// Xn: [b][n][d] f16.  Xv: [b][kt][d][k'] f16, kt = key-tile of 32, k' = key within tile.
__global__ __launch_bounds__(256, 2)
void prep_f16(const float* __restrict__ X, f16* __restrict__ Xn, f16* __restrict__ Xv)
{
  __shared__ f16 Lt[64 * 72];          // 64 keys x 64 d, pitch 72
  const int tid  = threadIdx.x;
  const int b    = blockIdx.x >> 7;
  const int kb64 = (blockIdx.x & 127) * 64;

  // phase 1: coalesced read, cvt, write Xn + stash in LDS
  {
    const int r = tid >> 2;            // key row 0..63
    const int c = (tid & 3) * 16;      // d col group
    const float* p = X + ((size_t)(b * NN + kb64 + r)) * DD + c;
    const float4 a0 = *(const float4*)(p);
    const float4 a1 = *(const float4*)(p + 4);
    const float4 a2 = *(const float4*)(p + 8);
    const float4 a3 = *(const float4*)(p + 12);
    f16x8 v0, v1;
    v0[0]=(f16)a0.x; v0[1]=(f16)a0.y; v0[2]=(f16)a0.z; v0[3]=(f16)a0.w;
    v0[4]=(f16)a1.x; v0[5]=(f16)a1.y; v0[6]=(f16)a1.z; v0[7]=(f16)a1.w;
    v1[0]=(f16)a2.x; v1[1]=(f16)a2.y; v1[2]=(f16)a2.z; v1[3]=(f16)a2.w;
    v1[4]=(f16)a3.x; v1[5]=(f16)a3.y; v1[6]=(f16)a3.z; v1[7]=(f16)a3.w;
    f16* dn = Xn + ((size_t)(b * NN + kb64 + r)) * DD + c;
    *(f16x8*)(dn)     = v0;
    *(f16x8*)(dn + 8) = v1;
    *(f16x8*)&Lt[r * 72 + c]     = v0;
    *(f16x8*)&Lt[r * 72 + c + 8] = v1;
  }
  __syncthreads();
  // phase 2: all 256 threads write transposed tiles.
  // thread -> (h = 32-key half, jh = 16-key subhalf, d): fully coalesced Xv writes.
  {
    const int h  = tid >> 7;           // which 32-key half
    const int r  = tid & 127;
    const int jh = r & 1;              // 16-key subgroup
    const int d  = r >> 1;             // d row 0..63
    union { f16 s[16]; f16x8 v[2]; } u;
    #pragma unroll
    for (int j = 0; j < 16; ++j) u.s[j] = Lt[(h * 32 + jh * 16 + j) * 72 + d];
    const int kt = (kb64 >> 5) + h;    // global 32-key tile index
    f16* dst = Xv + (((size_t)(b * (NN / 32) + kt)) * DD + d) * 32 + jh * 16;
    *(f16x8*)&dst[0] = u.v[0];
    *(f16x8*)&dst[8] = u.v[1];
  }
}

// ---------------- kernel B: attention + projection ----------------
// LDS: main loop uses only per-wave P scratch; epilogue overlays Hl/Wl/Lstar.
#define P_PITCH 36                       // f16; rows 72 B, b64 ops 8B-aligned, <=2-way banks
#define P_BYTES (64 * P_PITCH * 2)       // 4608 per wave
#define HL_PITCH 68
#define WL_OFF  (64 * HL_PITCH * 4)      // 17408
#define LST_OFF (2 * 64 * HL_PITCH * 4)  // 34816
#define SMEM_B  (NWAVES * P_BYTES)       // 36864 >= 35072 epilogue overlay

struct Frag { f16x8 ka[2][2]; f16x8 vb[4]; };

__global__ __launch_bounds__(512, 4)
void gconv_attn(const float* __restrict__ X, const f16* __restrict__ Xn,
                const f16* __restrict__ Xv, const float* __restrict__ W,
                float* __restrict__ out)
{
  __shared__ __align__(16) unsigned char smem[SMEM_B];

  const int tid  = threadIdx.x;
  const int lane = tid & 63;
  const int wave = tid >> 6;
  const int q15  = lane & 15;
  const int quad = lane >> 4;

  const int batch = blockIdx.x >> 7;
  const int qbase = (blockIdx.x & 127) * NQB;
  const float* Xb = X + (size_t)batch * NN * DD;

  f16* Pw = (f16*)(smem + wave * P_BYTES);

  // wave-local bases
  const f16* XnW = Xn + ((size_t)batch * NN + wave * KPW) * DD + q15 * DD + quad * 8;
  const f16* XvW = Xv + (((size_t)batch * (NN / 32) + wave * NTILES)) * DD * 32
                      + q15 * 32 + quad * 8;

  // ---- Q fragments (B-operand: n=q15 query, k=c*32+quad*8+j d), exp2 domain ----
  // m2 (per-query softmax shift) is folded into the MFMA C-initializer minit.
  f16x8 qf[4][2];
  f32x4 minit[4];
  float lrow[4];
  #pragma unroll
  for (int qt = 0; qt < 4; ++qt) {
    const float* qp = Xb + (size_t)(qbase + qt*16 + q15) * DD + quad*8;
    float nrm = 0.f;
    #pragma unroll
    for (int c = 0; c < 2; ++c) {
      const float4 a = *(const float4*)(qp + c*32);
      const float4 b = *(const float4*)(qp + c*32 + 4);
      float xs[8] = {a.x, a.y, a.z, a.w, b.x, b.y, b.z, b.w};
      f16x8 v;
      #pragma unroll
      for (int e = 0; e < 8; ++e) {
        const f16 ks = (f16)xs[e];
        const f16 qs = (f16)(xs[e] * LOG2E);
        nrm += (float)qs * (float)ks;
        v[e] = qs;
      }
      qf[qt][c] = v;
    }
    nrm += __shfl_xor(nrm, 16);
    nrm += __shfl_xor(nrm, 32);
    const float m2 = nrm + 2.0f;
    minit[qt] = (f32x4){-m2, -m2, -m2, -m2};
    lrow[qt] = 0.f;
  }

  f32x4 acc[4][4];
  #pragma unroll
  for (int a = 0; a < 4; ++a)
    #pragma unroll
    for (int b = 0; b < 4; ++b)
      acc[a][b] = (f32x4){0.f, 0.f, 0.f, 0.f};

  auto load_frag = [&](Frag& f, int t) {
    const f16* kn = XnW + (size_t)t * (KT * DD);
    #pragma unroll
    for (int g = 0; g < 2; ++g)
      #pragma unroll
      for (int c = 0; c < 2; ++c)
        f.ka[g][c] = *(const f16x8*)(kn + g * 16 * DD + c * 32);
    const f16* vn = XvW + (size_t)t * (DD * 32);
    #pragma unroll
    for (int mt = 0; mt < 4; ++mt)
      f.vb[mt] = *(const f16x8*)(vn + mt * 16 * 32);
  };

  const f16x2 kOnes = (f16x2){(f16)1.0f, (f16)1.0f};

  auto process = [&](const Frag& f) {
    #pragma unroll
    for (int qt = 0; qt < 4; ++qt) {
      #pragma unroll
      for (int g = 0; g < 2; ++g) {
        f32x4 s = __builtin_amdgcn_mfma_f32_16x16x32_f16(f.ka[g][0], qf[qt][0], minit[qt], 0, 0, 0);
        s = __builtin_amdgcn_mfma_f32_16x16x32_f16(f.ka[g][1], qf[qt][1], s, 0, 0, 0);
        const float p0 = __builtin_amdgcn_exp2f(s[0]);
        const float p1 = __builtin_amdgcn_exp2f(s[1]);
        const float p2 = __builtin_amdgcn_exp2f(s[2]);
        const float p3 = __builtin_amdgcn_exp2f(s[3]);
        union { f16x4 v; f16x2 h[2]; } pu;
        pu.h[0] = PKRTZ(p0, p1);
        pu.h[1] = PKRTZ(p2, p3);
        lrow[qt] = __builtin_amdgcn_fdot2(pu.h[0], kOnes, lrow[qt], false);
        lrow[qt] = __builtin_amdgcn_fdot2(pu.h[1], kOnes, lrow[qt], false);
        *(f16x4*)&Pw[(qt*16 + q15)*P_PITCH + g*16 + quad*4] = pu.v;
      }
    }
    #pragma unroll
    for (int qt = 0; qt < 4; ++qt) {
      union { f16x8 v; f16x4 h[2]; } pu;
      pu.h[0] = *(const f16x4*)&Pw[(qt*16 + q15)*P_PITCH + quad*8];
      pu.h[1] = *(const f16x4*)&Pw[(qt*16 + q15)*P_PITCH + quad*8 + 4];
      #pragma unroll
      for (int mt = 0; mt < 4; ++mt)
        acc[qt][mt] = __builtin_amdgcn_mfma_f32_16x16x32_f16(f.vb[mt], pu.v, acc[qt][mt], 0, 0, 0);
    }
  };

  // ---- software-pipelined main loop (register double-buffer) ----
  Frag f0, f1;
  load_frag(f0, 0);
  for (int t = 0; t < NTILES; t += 2) {
    const int t1 = (t + 1 < NTILES) ? t + 1 : t;
    const int t2 = (t + 2 < NTILES) ? t + 2 : t1;
    load_frag(f1, t1);
    process(f0);
    load_frag(f0, t2);
    process(f1);
  }

  // ========= merge across 8 key-split waves (shared m2: plain sums) =========
  __syncthreads();
  float* Hl    = (float*)smem;
  float* Wl    = (float*)(smem + WL_OFF);
  float* Lstar = (float*)(smem + LST_OFF);

  for (int i = tid; i < 64*HL_PITCH; i += 512) Hl[i] = 0.f;
  for (int i = tid; i < 64*64; i += 512) Wl[(i >> 6)*HL_PITCH + (i & 63)] = W[i];
  if (tid < 64) Lstar[tid] = 0.f;
  __syncthreads();

  #pragma unroll
  for (int qt = 0; qt < 4; ++qt) {
    float lr = lrow[qt];
    lr += __shfl_xor(lr, 16);
    lr += __shfl_xor(lr, 32);
    if (quad == 0) atomicAdd(&Lstar[qt*16 + q15], lr);
    #pragma unroll
    for (int mt = 0; mt < 4; ++mt)
      #pragma unroll
      for (int rr = 0; rr < 4; ++rr)
        atomicAdd(&Hl[(mt*16 + quad*4 + rr)*HL_PITCH + qt*16 + q15], acc[qt][mt][rr]);
  }
  __syncthreads();

  // ========= projection: out = (H / l) . W =========
  {
    const int qq = tid >> 3;           // query 0..63
    const int og = (tid & 7) * 8;      // out col group
    f32x4 o0 = (f32x4){0.f,0.f,0.f,0.f};
    f32x4 o1 = (f32x4){0.f,0.f,0.f,0.f};
    for (int d = 0; d < 64; ++d) {
      const float h = Hl[d*HL_PITCH + qq];
      const f32x4* wr = (const f32x4*)&Wl[d*HL_PITCH + og];
      o0 += h * wr[0];
      o1 += h * wr[1];
    }
    const float inv = 1.0f / Lstar[qq];
    float* op = out + ((size_t)batch * NN + qbase + qq) * DD + og;
    *(f32x4*)(op)     = o0 * inv;
    *(f32x4*)(op + 4) = o1 * inv;
  }
}

extern "C" void kernel_launch(void* const* d_in, const int* in_sizes, int n_in,
                              void* d_out, int out_size, void* d_ws, size_t ws_size,
                              hipStream_t stream) {
  const float* X = (const float*)d_in[0];   // [4, 8192, 64] fp32
  const float* W = (const float*)d_in[1];   // [64, 64] fp32
  float* out = (float*)d_out;               // [4, 8192, 64] fp32

  f16* Xn = (f16*)d_ws;                                  // 4 MiB
  f16* Xv = (f16*)((char*)d_ws + (size_t)4 * NN * DD * 2); // 4 MiB
  prep_f16<<<dim3(512), dim3(256), 0, stream>>>(X, Xn, Xv);
  gconv_attn<<<dim3(512), dim3(512), 0, stream>>>(X, Xn, Xv, W, out);
}

// Round 2
// 279.829 us; speedup vs baseline: 2.6791x; 2.6791x over previous
//
#include <hip/hip_runtime.h>
#include <math.h>

typedef _Float16 f16;
typedef _Float16 f16x2 __attribute__((ext_vector_type(2)));
typedef _Float16 f16x4 __attribute__((ext_vector_type(4)));
typedef _Float16 f16x8 __attribute__((ext_vector_type(8)));
typedef float    f32x4 __attribute__((ext_vector_type(4)));

#define PKRTZ(a, b) __builtin_bit_cast(f16x2, __builtin_amdgcn_cvt_pkrtz((a), (b)))

#define NN 8192
#define DD 64
#define KT 32
#define NWAVES 8              // per block
#define QPW 32                // queries per wave
#define NQB 64                // queries per block (2 qg * 32)
#define KSPLIT 4
#define KPW (NN / KSPLIT)     // 2048 keys per wave
#define NTILES (KPW / KT)     // 64

#define LOG2E 1.44269504088896f

// ---------------- kernel A: f32 -> f16 natural (Xn) + 32-key-tiled transpose (Xv) ----
// Xn: [b][n][d] f16.  Xv: [b][kt][d][k'] f16, kt = key-tile of 32, k' = key within tile.
__global__ __launch_bounds__(256, 2)
void prep_f16(const float* __restrict__ X, f16* __restrict__ Xn, f16* __restrict__ Xv)
{
  __shared__ f16 Lt[64 * 72];          // 64 keys x 64 d, pitch 72
  const int tid  = threadIdx.x;
  const int b    = blockIdx.x >> 7;
  const int kb64 = (blockIdx.x & 127) * 64;

  // phase 1: coalesced read, cvt, write Xn + stash in LDS
  {
    const int r = tid >> 2;            // key row 0..63
    const int c = (tid & 3) * 16;      // d col group
    const float* p = X + ((size_t)(b * NN + kb64 + r)) * DD + c;
    const float4 a0 = *(const float4*)(p);
    const float4 a1 = *(const float4*)(p + 4);
    const float4 a2 = *(const float4*)(p + 8);
    const float4 a3 = *(const float4*)(p + 12);
    f16x8 v0, v1;
    v0[0]=(f16)a0.x; v0[1]=(f16)a0.y; v0[2]=(f16)a0.z; v0[3]=(f16)a0.w;
    v0[4]=(f16)a1.x; v0[5]=(f16)a1.y; v0[6]=(f16)a1.z; v0[7]=(f16)a1.w;
    v1[0]=(f16)a2.x; v1[1]=(f16)a2.y; v1[2]=(f16)a2.z; v1[3]=(f16)a2.w;
    v1[4]=(f16)a3.x; v1[5]=(f16)a3.y; v1[6]=(f16)a3.z; v1[7]=(f16)a3.w;
    f16* dn = Xn + ((size_t)(b * NN + kb64 + r)) * DD + c;
    *(f16x8*)(dn)     = v0;
    *(f16x8*)(dn + 8) = v1;
    *(f16x8*)&Lt[r * 72 + c]     = v0;
    *(f16x8*)&Lt[r * 72 + c + 8] = v1;
  }
  __syncthreads();
  // phase 2: all 256 threads write transposed tiles (coalesced).
  {
    const int h  = tid >> 7;           // which 32-key half
    const int r  = tid & 127;
    const int jh = r & 1;              // 16-key subgroup
    const int d  = r >> 1;             // d row 0..63
    union { f16 s[16]; f16x8 v[2]; } u;
    #pragma unroll
    for (int j = 0; j < 16; ++j) u.s[j] = Lt[(h * 32 + jh * 16 + j) * 72 + d];
    const int kt = (kb64 >> 5) + h;    // global 32-key tile index
    f16* dst = Xv + (((size_t)(b * (NN / 32) + kt)) * DD + d) * 32 + jh * 16;
    *(f16x8*)&dst[0] = u.v[0];
    *(f16x8*)&dst[8] = u.v[1];
  }
}

// ---------------- kernel B: attention + projection ----------------
// 8 waves = 2 query-groups (32 q each) x 4 key-splits (2048 keys each).
// Register budget target: <=128 total (VGPR+ACC) -> 4 waves/SIMD, 16 waves/CU.
#define P_PITCH 36                       // f16; rows 72 B
#define P_BYTES (QPW * P_PITCH * 2)      // 2304 per wave
#define HL_PITCH 68
#define WL_OFF  (64 * HL_PITCH * 4)      // 17408
#define LST_OFF (2 * 64 * HL_PITCH * 4)  // 34816
#define SMEM_B  (LST_OFF + 64 * 4)       // 35072 (>= 8*P_BYTES = 18432)

struct Frag { f16x8 ka[2][2]; f16x8 vb[4]; };

__global__ __launch_bounds__(512, 2)
void gconv_attn(const float* __restrict__ X, const f16* __restrict__ Xn,
                const f16* __restrict__ Xv, const float* __restrict__ W,
                float* __restrict__ out)
{
  __shared__ __align__(16) unsigned char smem[SMEM_B];

  const int tid  = threadIdx.x;
  const int lane = tid & 63;
  const int wave = tid >> 6;
  const int q15  = lane & 15;
  const int quad = lane >> 4;
  const int qg   = wave & 1;          // query group (32 queries)
  const int ks   = wave >> 1;         // key split (2048 keys)

  const int batch = blockIdx.x >> 7;
  const int qbase = (blockIdx.x & 127) * NQB;
  const float* Xb = X + (size_t)batch * NN * DD;

  f16* Pw = (f16*)(smem + wave * P_BYTES);

  // wave-local bases
  const f16* XnW = Xn + ((size_t)batch * NN + ks * KPW) * DD + q15 * DD + quad * 8;
  const f16* XvW = Xv + (((size_t)batch * (NN / 32) + ks * NTILES)) * DD * 32
                      + q15 * 32 + quad * 8;

  // ---- Q fragments (B-operand), exp2 domain; m2 folded into MFMA C-init ----
  f16x8 qf[2][2];
  f32x4 minit[2];
  float lrow[2];
  #pragma unroll
  for (int qt = 0; qt < 2; ++qt) {
    const float* qp = Xb + (size_t)(qbase + qg*32 + qt*16 + q15) * DD + quad*8;
    float nrm = 0.f;
    #pragma unroll
    for (int c = 0; c < 2; ++c) {
      const float4 a = *(const float4*)(qp + c*32);
      const float4 b = *(const float4*)(qp + c*32 + 4);
      float xs[8] = {a.x, a.y, a.z, a.w, b.x, b.y, b.z, b.w};
      f16x8 v;
      #pragma unroll
      for (int e = 0; e < 8; ++e) {
        const f16 kv = (f16)xs[e];
        const f16 qs = (f16)(xs[e] * LOG2E);
        nrm += (float)qs * (float)kv;
        v[e] = qs;
      }
      qf[qt][c] = v;
    }
    nrm += __shfl_xor(nrm, 16);
    nrm += __shfl_xor(nrm, 32);
    const float m2 = nrm + 2.0f;
    minit[qt] = (f32x4){-m2, -m2, -m2, -m2};
    lrow[qt] = 0.f;
  }

  f32x4 acc[2][4];
  #pragma unroll
  for (int a = 0; a < 2; ++a)
    #pragma unroll
    for (int b = 0; b < 4; ++b)
      acc[a][b] = (f32x4){0.f, 0.f, 0.f, 0.f};

  const f16x2 kOnes = (f16x2){(f16)1.0f, (f16)1.0f};

  Frag f;
  // prologue loads for tile 0
  {
    const f16* kn = XnW;
    #pragma unroll
    for (int g = 0; g < 2; ++g)
      #pragma unroll
      for (int c = 0; c < 2; ++c)
        f.ka[g][c] = *(const f16x8*)(kn + g * 16 * DD + c * 32);
    const f16* vn = XvW;
    #pragma unroll
    for (int mt = 0; mt < 4; ++mt)
      f.vb[mt] = *(const f16x8*)(vn + mt * 16 * 32);
  }

  for (int t = 0; t < NTILES; ++t) {
    const int tn = (t + 1 < NTILES) ? t + 1 : t;

    // ---- QK^T (consumes f.ka) ----
    f32x4 sqk[2][2];
    #pragma unroll
    for (int qt = 0; qt < 2; ++qt)
      #pragma unroll
      for (int g = 0; g < 2; ++g) {
        f32x4 s = __builtin_amdgcn_mfma_f32_16x16x32_f16(f.ka[g][0], qf[qt][0], minit[qt], 0, 0, 0);
        sqk[qt][g] = __builtin_amdgcn_mfma_f32_16x16x32_f16(f.ka[g][1], qf[qt][1], s, 0, 0, 0);
      }

    // ---- prefetch next ka (f.ka now dead) ----
    {
      const f16* kn = XnW + (size_t)tn * (KT * DD);
      #pragma unroll
      for (int g = 0; g < 2; ++g)
        #pragma unroll
        for (int c = 0; c < 2; ++c)
          f.ka[g][c] = *(const f16x8*)(kn + g * 16 * DD + c * 32);
    }

    // ---- softmax: exp2, pack to f16, row-sum via fdot2, stash P in LDS ----
    #pragma unroll
    for (int qt = 0; qt < 2; ++qt)
      #pragma unroll
      for (int g = 0; g < 2; ++g) {
        const float p0 = __builtin_amdgcn_exp2f(sqk[qt][g][0]);
        const float p1 = __builtin_amdgcn_exp2f(sqk[qt][g][1]);
        const float p2 = __builtin_amdgcn_exp2f(sqk[qt][g][2]);
        const float p3 = __builtin_amdgcn_exp2f(sqk[qt][g][3]);
        union { f16x4 v; f16x2 h[2]; } pu;
        pu.h[0] = PKRTZ(p0, p1);
        pu.h[1] = PKRTZ(p2, p3);
        lrow[qt] = __builtin_amdgcn_fdot2(pu.h[0], kOnes, lrow[qt], false);
        lrow[qt] = __builtin_amdgcn_fdot2(pu.h[1], kOnes, lrow[qt], false);
        *(f16x4*)&Pw[(qt*16 + q15)*P_PITCH + g*16 + quad*4] = pu.v;
      }

    // ---- PV (consumes f.vb) ----
    #pragma unroll
    for (int qt = 0; qt < 2; ++qt) {
      union { f16x8 v; f16x4 h[2]; } pu;
      pu.h[0] = *(const f16x4*)&Pw[(qt*16 + q15)*P_PITCH + quad*8];
      pu.h[1] = *(const f16x4*)&Pw[(qt*16 + q15)*P_PITCH + quad*8 + 4];
      #pragma unroll
      for (int mt = 0; mt < 4; ++mt)
        acc[qt][mt] = __builtin_amdgcn_mfma_f32_16x16x32_f16(f.vb[mt], pu.v, acc[qt][mt], 0, 0, 0);
    }

    // ---- prefetch next vb (f.vb now dead) ----
    {
      const f16* vn = XvW + (size_t)tn * (DD * 32);
      #pragma unroll
      for (int mt = 0; mt < 4; ++mt)
        f.vb[mt] = *(const f16x8*)(vn + mt * 16 * 32);
    }
  }

  // ========= merge across 4 key-split waves (shared m2: plain sums) =========
  __syncthreads();
  float* Hl    = (float*)smem;
  float* Wl    = (float*)(smem + WL_OFF);
  float* Lstar = (float*)(smem + LST_OFF);

  for (int i = tid; i < 64*HL_PITCH; i += 512) Hl[i] = 0.f;
  for (int i = tid; i < 64*64; i += 512) Wl[(i >> 6)*HL_PITCH + (i & 63)] = W[i];
  if (tid < 64) Lstar[tid] = 0.f;
  __syncthreads();

  #pragma unroll
  for (int qt = 0; qt < 2; ++qt) {
    float lr = lrow[qt];
    lr += __shfl_xor(lr, 16);
    lr += __shfl_xor(lr, 32);
    if (quad == 0) atomicAdd(&Lstar[qg*32 + qt*16 + q15], lr);
    #pragma unroll
    for (int mt = 0; mt < 4; ++mt)
      #pragma unroll
      for (int rr = 0; rr < 4; ++rr)
        atomicAdd(&Hl[(mt*16 + quad*4 + rr)*HL_PITCH + qg*32 + qt*16 + q15], acc[qt][mt][rr]);
  }
  __syncthreads();

  // ========= projection: out = (H / l) . W =========
  {
    const int qq = tid >> 3;           // query 0..63
    const int og = (tid & 7) * 8;      // out col group
    f32x4 o0 = (f32x4){0.f,0.f,0.f,0.f};
    f32x4 o1 = (f32x4){0.f,0.f,0.f,0.f};
    for (int d = 0; d < 64; ++d) {
      const float h = Hl[d*HL_PITCH + qq];
      const f32x4* wr = (const f32x4*)&Wl[d*HL_PITCH + og];
      o0 += h * wr[0];
      o1 += h * wr[1];
    }
    const float inv = 1.0f / Lstar[qq];
    float* op = out + ((size_t)batch * NN + qbase + qq) * DD + og;
    *(f32x4*)(op)     = o0 * inv;
    *(f32x4*)(op + 4) = o1 * inv;
  }
}

extern "C" void kernel_launch(void* const* d_in, const int* in_sizes, int n_in,
                              void* d_out, int out_size, void* d_ws, size_t ws_size,
                              hipStream_t stream) {
  const float* X = (const float*)d_in[0];   // [4, 8192, 64] fp32
  const float* W = (const float*)d_in[1];   // [64, 64] fp32
  float* out = (float*)d_out;               // [4, 8192, 64] fp32

  f16* Xn = (f16*)d_ws;                                  // 4 MiB
  f16* Xv = (f16*)((char*)d_ws + (size_t)4 * NN * DD * 2); // 4 MiB
  prep_f16<<<dim3(512), dim3(256), 0, stream>>>(X, Xn, Xv);
  gconv_attn<<<dim3(512), dim3(512), 0, stream>>>(X, Xn, Xv, W, out);
}

// Round 3
// 203.059 us; speedup vs baseline: 3.6920x; 1.3781x over previous
//
#include <hip/hip_runtime.h>
#include <math.h>

typedef _Float16 f16;
typedef _Float16 f16x2 __attribute__((ext_vector_type(2)));
typedef _Float16 f16x4 __attribute__((ext_vector_type(4)));
typedef _Float16 f16x8 __attribute__((ext_vector_type(8)));
typedef float    f32x4 __attribute__((ext_vector_type(4)));

#define PKRTZ(a, b) __builtin_bit_cast(f16x2, __builtin_amdgcn_cvt_pkrtz((a), (b)))

#define NN 8192
#define DD 64
#define KT 32
#define NQB 64
#define NWAVES 4
#define KPW (NN / NWAVES)      // 2048 keys per wave
#define NTILES (KPW / KT)      // 64

#define LOG2E 1.44269504088896f

// ---------------- kernel A: f32 -> f16 natural (Xn) + 32-key-tiled transpose (Xv) ----
// Xn: [b][n][d] f16.  Xv: [b][kt][d][k'] f16, kt = key-tile of 32, k' = key within tile.
__global__ __launch_bounds__(256, 2)
void prep_f16(const float* __restrict__ X, f16* __restrict__ Xn, f16* __restrict__ Xv)
{
  __shared__ f16 Lt[64 * 72];          // 64 keys x 64 d, pitch 72
  const int tid  = threadIdx.x;
  const int b    = blockIdx.x >> 7;
  const int kb64 = (blockIdx.x & 127) * 64;

  // phase 1: coalesced read, cvt, write Xn + stash in LDS
  {
    const int r = tid >> 2;            // key row 0..63
    const int c = (tid & 3) * 16;      // d col group
    const float* p = X + ((size_t)(b * NN + kb64 + r)) * DD + c;
    const float4 a0 = *(const float4*)(p);
    const float4 a1 = *(const float4*)(p + 4);
    const float4 a2 = *(const float4*)(p + 8);
    const float4 a3 = *(const float4*)(p + 12);
    f16x8 v0, v1;
    v0[0]=(f16)a0.x; v0[1]=(f16)a0.y; v0[2]=(f16)a0.z; v0[3]=(f16)a0.w;
    v0[4]=(f16)a1.x; v0[5]=(f16)a1.y; v0[6]=(f16)a1.z; v0[7]=(f16)a1.w;
    v1[0]=(f16)a2.x; v1[1]=(f16)a2.y; v1[2]=(f16)a2.z; v1[3]=(f16)a2.w;
    v1[4]=(f16)a3.x; v1[5]=(f16)a3.y; v1[6]=(f16)a3.z; v1[7]=(f16)a3.w;
    f16* dn = Xn + ((size_t)(b * NN + kb64 + r)) * DD + c;
    *(f16x8*)(dn)     = v0;
    *(f16x8*)(dn + 8) = v1;
    *(f16x8*)&Lt[r * 72 + c]     = v0;
    *(f16x8*)&Lt[r * 72 + c + 8] = v1;
  }
  __syncthreads();
  // phase 2: all 256 threads write transposed tiles (coalesced).
  {
    const int h  = tid >> 7;           // which 32-key half
    const int r  = tid & 127;
    const int jh = r & 1;              // 16-key subgroup
    const int d  = r >> 1;             // d row 0..63
    union { f16 s[16]; f16x8 v[2]; } u;
    #pragma unroll
    for (int j = 0; j < 16; ++j) u.s[j] = Lt[(h * 32 + jh * 16 + j) * 72 + d];
    const int kt = (kb64 >> 5) + h;    // global 32-key tile index
    f16* dst = Xv + (((size_t)(b * (NN / 32) + kt)) * DD + d) * 32 + jh * 16;
    *(f16x8*)&dst[0] = u.v[0];
    *(f16x8*)&dst[8] = u.v[1];
  }
}

// ---------------- kernel B: attention + projection ----------------
// Fat waves (R0 shape): 4 waves x 64 queries x 2048 keys.
// New: cross-tile software pipeline — PV runs one tile behind QK/softmax,
// P double-buffered in LDS, vb double-buffered in regs, unroll-by-2 for
// static buffer indices.
#define P_PITCH 36                       // f16; rows 72 B
#define P_HALF  (64 * P_PITCH)           // f16 elems per buffer (4608 B)
#define P_BYTES (2 * P_HALF * 2)         // 9216 B per wave (two buffers)
#define HL_PITCH 68
#define WL_OFF  (64 * HL_PITCH * 4)      // 17408
#define LST_OFF (2 * 64 * HL_PITCH * 4)  // 34816
#define SMEM_B  (NWAVES * P_BYTES)       // 36864 (>= 35072 epilogue overlay)

__global__ __launch_bounds__(256, 2)
void gconv_attn(const float* __restrict__ X, const f16* __restrict__ Xn,
                const f16* __restrict__ Xv, const float* __restrict__ W,
                float* __restrict__ out)
{
  __shared__ __align__(16) unsigned char smem[SMEM_B];

  const int tid  = threadIdx.x;
  const int lane = tid & 63;
  const int wave = tid >> 6;
  const int q15  = lane & 15;
  const int quad = lane >> 4;

  const int batch = blockIdx.x >> 7;
  const int qbase = (blockIdx.x & 127) * NQB;
  const float* Xb = X + (size_t)batch * NN * DD;

  f16* PwA = (f16*)(smem + wave * P_BYTES);
  f16* PwB = PwA + P_HALF;

  // wave-local bases
  const f16* XnW = Xn + ((size_t)batch * NN + wave * KPW) * DD + q15 * DD + quad * 8;
  const f16* XvW = Xv + (((size_t)batch * (NN / 32) + wave * NTILES)) * DD * 32
                      + q15 * 32 + quad * 8;

  // ---- Q fragments (B-operand), exp2 domain; m2 folded into MFMA C-init ----
  f16x8 qf[4][2];
  f32x4 minit[4];
  float lrow[4];
  #pragma unroll
  for (int qt = 0; qt < 4; ++qt) {
    const float* qp = Xb + (size_t)(qbase + qt*16 + q15) * DD + quad*8;
    float nrm = 0.f;
    #pragma unroll
    for (int c = 0; c < 2; ++c) {
      const float4 a = *(const float4*)(qp + c*32);
      const float4 b = *(const float4*)(qp + c*32 + 4);
      float xs[8] = {a.x, a.y, a.z, a.w, b.x, b.y, b.z, b.w};
      f16x8 v;
      #pragma unroll
      for (int e = 0; e < 8; ++e) {
        const f16 kv = (f16)xs[e];
        const f16 qs = (f16)(xs[e] * LOG2E);
        nrm += (float)qs * (float)kv;
        v[e] = qs;
      }
      qf[qt][c] = v;
    }
    nrm += __shfl_xor(nrm, 16);
    nrm += __shfl_xor(nrm, 32);
    const float m2 = nrm + 2.0f;
    minit[qt] = (f32x4){-m2, -m2, -m2, -m2};
    lrow[qt] = 0.f;
  }

  f32x4 acc[4][4];
  #pragma unroll
  for (int a = 0; a < 4; ++a)
    #pragma unroll
    for (int b = 0; b < 4; ++b)
      acc[a][b] = (f32x4){0.f, 0.f, 0.f, 0.f};

  const f16x2 kOnes = (f16x2){(f16)1.0f, (f16)1.0f};

  // ---- pipeline stage lambdas ----
  f16x8 ka[2][2], vbA[4], vbB[4];
  f32x4 sqk[4][2];

  auto LDK = [&](int t) {
    const f16* kn = XnW + (size_t)t * (KT * DD);
    #pragma unroll
    for (int g = 0; g < 2; ++g)
      #pragma unroll
      for (int c = 0; c < 2; ++c)
        ka[g][c] = *(const f16x8*)(kn + g * 16 * DD + c * 32);
  };
  auto LDV = [&](f16x8 (&vb)[4], int t) {
    const f16* vn = XvW + (size_t)t * (DD * 32);
    #pragma unroll
    for (int mt = 0; mt < 4; ++mt)
      vb[mt] = *(const f16x8*)(vn + mt * 16 * 32);
  };
  auto QK = [&]() {
    #pragma unroll
    for (int qt = 0; qt < 4; ++qt)
      #pragma unroll
      for (int g = 0; g < 2; ++g) {
        f32x4 s = __builtin_amdgcn_mfma_f32_16x16x32_f16(ka[g][0], qf[qt][0], minit[qt], 0, 0, 0);
        sqk[qt][g] = __builtin_amdgcn_mfma_f32_16x16x32_f16(ka[g][1], qf[qt][1], s, 0, 0, 0);
      }
  };
  auto SM = [&](f16* Pd) {
    #pragma unroll
    for (int qt = 0; qt < 4; ++qt)
      #pragma unroll
      for (int g = 0; g < 2; ++g) {
        const float p0 = __builtin_amdgcn_exp2f(sqk[qt][g][0]);
        const float p1 = __builtin_amdgcn_exp2f(sqk[qt][g][1]);
        const float p2 = __builtin_amdgcn_exp2f(sqk[qt][g][2]);
        const float p3 = __builtin_amdgcn_exp2f(sqk[qt][g][3]);
        union { f16x4 v; f16x2 h[2]; } pu;
        pu.h[0] = PKRTZ(p0, p1);
        pu.h[1] = PKRTZ(p2, p3);
        lrow[qt] = __builtin_amdgcn_fdot2(pu.h[0], kOnes, lrow[qt], false);
        lrow[qt] = __builtin_amdgcn_fdot2(pu.h[1], kOnes, lrow[qt], false);
        *(f16x4*)&Pd[(qt*16 + q15)*P_PITCH + g*16 + quad*4] = pu.v;
      }
  };
  auto PV = [&](const f16x8 (&vb)[4], const f16* Ps) {
    #pragma unroll
    for (int qt = 0; qt < 4; ++qt) {
      union { f16x8 v; f16x4 h[2]; } pu;
      pu.h[0] = *(const f16x4*)&Ps[(qt*16 + q15)*P_PITCH + quad*8];
      pu.h[1] = *(const f16x4*)&Ps[(qt*16 + q15)*P_PITCH + quad*8 + 4];
      #pragma unroll
      for (int mt = 0; mt < 4; ++mt)
        acc[qt][mt] = __builtin_amdgcn_mfma_f32_16x16x32_f16(vb[mt], pu.v, acc[qt][mt], 0, 0, 0);
    }
  };

  // ---- prologue: tile 0 through SM; even tiles -> PwA/vbA, odd -> PwB/vbB ----
  LDK(0);
  LDV(vbA, 0);
  QK();                 // tile 0
  LDK(1);
  SM(PwA);              // P(0) -> bufA
  LDV(vbB, 1);

  // ---- steady state: pairs (t odd, t+1 even), t = 1,3,...,61 ----
  for (int t = 1; t < NTILES - 1; t += 2) {
    // iter t (odd)
    QK();               // tile t (ka holds t)
    LDK(t + 1);
    PV(vbA, PwA);       // tile t-1 (even)
    LDV(vbA, t + 1);    // next even tile
    SM(PwB);            // P(t) -> bufB
    // iter t+1 (even)
    QK();               // tile t+1
    LDK(t + 2);
    PV(vbB, PwB);       // tile t (odd)
    LDV(vbB, t + 2);    // next odd tile
    SM(PwA);            // P(t+1) -> bufA
  }

  // ---- epilogue: tile 63 (odd), then drain PV(62), PV(63) ----
  QK();                 // tile 63
  PV(vbA, PwA);         // tile 62 (even)
  SM(PwB);              // P(63) -> bufB
  PV(vbB, PwB);         // tile 63

  // ========= merge across 4 key-split waves (shared m2: plain sums) =========
  __syncthreads();
  float* Hl    = (float*)smem;
  float* Wl    = (float*)(smem + WL_OFF);
  float* Lstar = (float*)(smem + LST_OFF);

  for (int i = tid; i < 64*HL_PITCH; i += 256) Hl[i] = 0.f;
  for (int i = tid; i < 64*64; i += 256) Wl[(i >> 6)*HL_PITCH + (i & 63)] = W[i];
  if (tid < 64) Lstar[tid] = 0.f;
  __syncthreads();

  #pragma unroll
  for (int qt = 0; qt < 4; ++qt) {
    float lr = lrow[qt];
    lr += __shfl_xor(lr, 16);
    lr += __shfl_xor(lr, 32);
    if (quad == 0) atomicAdd(&Lstar[qt*16 + q15], lr);
    #pragma unroll
    for (int mt = 0; mt < 4; ++mt)
      #pragma unroll
      for (int rr = 0; rr < 4; ++rr)
        atomicAdd(&Hl[(mt*16 + quad*4 + rr)*HL_PITCH + qt*16 + q15], acc[qt][mt][rr]);
  }
  __syncthreads();

  // ========= projection: out = (H / l) . W =========
  {
    const int qq = tid >> 2;
    const int og = (tid & 3) * 16;
    f32x4 o[4];
    #pragma unroll
    for (int i = 0; i < 4; ++i) o[i] = (f32x4){0.f,0.f,0.f,0.f};
    for (int d = 0; d < 64; ++d) {
      const float h = Hl[d*HL_PITCH + qq];
      const f32x4* wr = (const f32x4*)&Wl[d*HL_PITCH + og];
      #pragma unroll
      for (int i = 0; i < 4; ++i) o[i] += h * wr[i];
    }
    const float inv = 1.0f / Lstar[qq];
    float* op = out + ((size_t)batch * NN + qbase + qq) * DD + og;
    #pragma unroll
    for (int i = 0; i < 4; ++i)
      *(f32x4*)(op + i*4) = o[i] * inv;
  }
}

extern "C" void kernel_launch(void* const* d_in, const int* in_sizes, int n_in,
                              void* d_out, int out_size, void* d_ws, size_t ws_size,
                              hipStream_t stream) {
  const float* X = (const float*)d_in[0];   // [4, 8192, 64] fp32
  const float* W = (const float*)d_in[1];   // [64, 64] fp32
  float* out = (float*)d_out;               // [4, 8192, 64] fp32

  f16* Xn = (f16*)d_ws;                                  // 4 MiB
  f16* Xv = (f16*)((char*)d_ws + (size_t)4 * NN * DD * 2); // 4 MiB
  prep_f16<<<dim3(512), dim3(256), 0, stream>>>(X, Xn, Xv);
  gconv_attn<<<dim3(512), dim3(256), 0, stream>>>(X, Xn, Xv, W, out);
}